// Round 5
// baseline (722.518 us; speedup 1.0000x reference)
//
#include <hip/hip_runtime.h>
#include <math.h>

#define HIDDEN 64
#define N_LAYERS 4
#define N_CLASSES 10
#define N_GRAPHS 512
#define BSH 5                       // bucket shift: 32 nodes per bucket
#define BNODES (1 << BSH)

// ---------------- degree count (int) ----------------
__global__ __launch_bounds__(256) void k_count(const int* __restrict__ dst,
                                               int* __restrict__ cnt, int E) {
    int i = blockIdx.x * 256 + threadIdx.x;
    if (i < E) atomicAdd(&cnt[dst[i]], 1);
}

// ---------------- exclusive scan over cnt -> rowptr (1024 elems/block) ----------------
__global__ __launch_bounds__(256) void k_scan1(const int* __restrict__ cnt,
                                               int* __restrict__ partial, int n) {
    __shared__ int sd[256];
    int t = threadIdx.x;
    int base = blockIdx.x * 1024 + t * 4;
    int sum = 0;
    #pragma unroll
    for (int i = 0; i < 4; ++i) { int idx = base + i; if (idx < n) sum += cnt[idx]; }
    sd[t] = sum; __syncthreads();
    for (int o = 128; o > 0; o >>= 1) { if (t < o) sd[t] += sd[t + o]; __syncthreads(); }
    if (t == 0) partial[blockIdx.x] = sd[0];
}

__global__ __launch_bounds__(256) void k_scan2(int* __restrict__ partial, int nb) {
    __shared__ int s[256];
    int t = threadIdx.x;
    int v = (t < nb) ? partial[t] : 0;
    s[t] = v; __syncthreads();
    for (int o = 1; o < 256; o <<= 1) {
        int x = (t >= o) ? s[t - o] : 0;
        __syncthreads();
        s[t] += x;
        __syncthreads();
    }
    if (t < nb) partial[t] = s[t] - v;   // exclusive
}

// scan3 emits rowptr, dis = rsqrt(deg), and per-bucket cursors bcur[b]=rowptr[b<<BSH]
__global__ __launch_bounds__(256) void k_scan3(const int* __restrict__ cnt,
                                               const int* __restrict__ partial,
                                               int* __restrict__ rowptr,
                                               float* __restrict__ dis,
                                               int* __restrict__ bcur,
                                               int n, int E) {
    __shared__ int s[256];
    int t = threadIdx.x;
    int base = blockIdx.x * 1024 + t * 4;
    int v[4]; int tsum = 0;
    #pragma unroll
    for (int i = 0; i < 4; ++i) { int idx = base + i; v[i] = (idx < n) ? cnt[idx] : 0; tsum += v[i]; }
    s[t] = tsum; __syncthreads();
    for (int o = 1; o < 256; o <<= 1) {
        int x = (t >= o) ? s[t - o] : 0;
        __syncthreads();
        s[t] += x;
        __syncthreads();
    }
    int inc = s[t];
    int run = partial[blockIdx.x] + inc - tsum;   // exclusive offset
    #pragma unroll
    for (int i = 0; i < 4; ++i) {
        int idx = base + i;
        if (idx < n) {
            rowptr[idx] = run;
            dis[idx] = rsqrtf((float)v[i] + 1.0f);   // + self-loop
            if ((idx & (BNODES - 1)) == 0) bcur[idx >> BSH] = run;
        }
        run += v[i];
    }
    if (blockIdx.x == 0 && t == 0) rowptr[n] = E;
}

// ---------------- phase A: bin edges by dst bucket, packed (src<<BSH)|(dst&31) ----------------
// requires src < 2^(32-BSH-? ) : N=100000 < 2^17, 17+5=22 bits — fits easily.
__global__ __launch_bounds__(256) void k_bin(const int* __restrict__ src,
                                             const int* __restrict__ dst,
                                             int* __restrict__ bcur,
                                             int* __restrict__ packed, int E) {
    int e = blockIdx.x * 256 + threadIdx.x;
    if (e < E) {
        int s = src[e], d = dst[e];
        int p = atomicAdd(&bcur[d >> BSH], 1);
        packed[p] = (s << BSH) | (d & (BNODES - 1));
    }
}

// ---------------- phase B: per-bucket CSR fill with LDS cursors ----------------
__global__ __launch_bounds__(256) void k_fill2(const int* __restrict__ packed,
                                               const int* __restrict__ rowptr,
                                               int* __restrict__ csr_src,
                                               int N, int nbuckets) {
    __shared__ int cur[BNODES];
    int b = blockIdx.x;
    if (b >= nbuckets) return;
    int t = threadIdx.x;
    int node0 = b << BSH;
    int nend  = min(node0 + BNODES, N);
    if (t < BNODES && node0 + t < N) cur[t] = rowptr[node0 + t];
    __syncthreads();
    int beg = rowptr[node0];
    int end = rowptr[nend];
    for (int j = beg + t; j < end; j += 256) {
        int v = packed[j];
        int s = v >> BSH;
        int local = v & (BNODES - 1);
        int slot = atomicAdd(&cur[local], 1);
        csr_src[slot] = s;
    }
}

// ---------------- GEMM: [N,64] @ [64,64], grid-stride 64-row chunks ----------------
// mode 0 (encoder):  outg[r] = dis[r] * (v + b)
// mode 1 (mid layer):outg[r] = dis[r] * silu(v + b)
// mode 2 (last):     pooled[batch[r]] += silu(v + b)   (atomic, batch-run combined)
__global__ __launch_bounds__(256, 4) void k_gemm(const float* __restrict__ in,
                                                 const float* __restrict__ W,
                                                 const float* __restrict__ bias,
                                                 const float* __restrict__ dis,
                                                 const int* __restrict__ batch,
                                                 float* __restrict__ outg,
                                                 float* __restrict__ pooled,
                                                 int N, int nchunks, int mode) {
    __shared__ float Ws[64 * 64];
    int tid = threadIdx.x;
    #pragma unroll
    for (int i = 0; i < 4; ++i)
        ((float4*)Ws)[tid + i * 256] = ((const float4*)W)[tid + i * 256];
    __syncthreads();

    int cq = tid & 15;          // column quad -> c0
    int rg = tid >> 4;          // row group -> 4 rows
    int c0 = cq * 4;
    float4 b4 = *(const float4*)(bias + c0);

    for (int chunk = blockIdx.x; chunk < nchunks; chunk += gridDim.x) {
        int row0 = chunk * 64 + rg * 4;
        const float4* xr0 = (const float4*)(in + (size_t)((row0 + 0 < N) ? row0 + 0 : 0) * 64);
        const float4* xr1 = (const float4*)(in + (size_t)((row0 + 1 < N) ? row0 + 1 : 0) * 64);
        const float4* xr2 = (const float4*)(in + (size_t)((row0 + 2 < N) ? row0 + 2 : 0) * 64);
        const float4* xr3 = (const float4*)(in + (size_t)((row0 + 3 < N) ? row0 + 3 : 0) * 64);

        float4 a0 = make_float4(0.f, 0.f, 0.f, 0.f);
        float4 a1 = a0, a2 = a0, a3 = a0;

        #pragma unroll 4
        for (int kc = 0; kc < 16; ++kc) {
            float4 x0 = xr0[kc];
            float4 x1 = xr1[kc];
            float4 x2 = xr2[kc];
            float4 x3 = xr3[kc];
            float4 w0 = *(const float4*)(Ws + (kc * 4 + 0) * 64 + c0);
            float4 w1 = *(const float4*)(Ws + (kc * 4 + 1) * 64 + c0);
            float4 w2 = *(const float4*)(Ws + (kc * 4 + 2) * 64 + c0);
            float4 w3 = *(const float4*)(Ws + (kc * 4 + 3) * 64 + c0);
            #define ROWFMA(ACC, XV)                                             \
                ACC.x += XV.x * w0.x + XV.y * w1.x + XV.z * w2.x + XV.w * w3.x; \
                ACC.y += XV.x * w0.y + XV.y * w1.y + XV.z * w2.y + XV.w * w3.y; \
                ACC.z += XV.x * w0.z + XV.y * w1.z + XV.z * w2.z + XV.w * w3.z; \
                ACC.w += XV.x * w0.w + XV.y * w1.w + XV.z * w2.w + XV.w * w3.w;
            ROWFMA(a0, x0)
            ROWFMA(a1, x1)
            ROWFMA(a2, x2)
            ROWFMA(a3, x3)
            #undef ROWFMA
        }

        float4 acc[4] = {a0, a1, a2, a3};
        if (mode == 0) {
            #pragma unroll
            for (int i = 0; i < 4; ++i) {
                int r = row0 + i;
                if (r < N) {
                    float ds = dis[r];
                    float4 v = acc[i];
                    float4 o = make_float4(ds * (v.x + b4.x), ds * (v.y + b4.y),
                                           ds * (v.z + b4.z), ds * (v.w + b4.w));
                    *(float4*)(outg + (size_t)r * 64 + c0) = o;
                }
            }
        } else if (mode == 1) {
            #pragma unroll
            for (int i = 0; i < 4; ++i) {
                int r = row0 + i;
                if (r < N) {
                    float ds = dis[r];
                    float4 v = acc[i];
                    float sx = v.x + b4.x, sy = v.y + b4.y, sz = v.z + b4.z, sw = v.w + b4.w;
                    float4 o;
                    o.x = ds * (sx / (1.0f + expf(-sx)));
                    o.y = ds * (sy / (1.0f + expf(-sy)));
                    o.z = ds * (sz / (1.0f + expf(-sz)));
                    o.w = ds * (sw / (1.0f + expf(-sw)));
                    *(float4*)(outg + (size_t)r * 64 + c0) = o;
                }
            }
        } else {
            float rx = 0.f, ry = 0.f, rz = 0.f, rw = 0.f;
            int cur = -1;
            #pragma unroll
            for (int i = 0; i < 4; ++i) {
                int r = row0 + i;
                if (r < N) {
                    int bi = batch[r];
                    float4 v = acc[i];
                    float sx = v.x + b4.x, sy = v.y + b4.y, sz = v.z + b4.z, sw = v.w + b4.w;
                    sx = sx / (1.0f + expf(-sx));
                    sy = sy / (1.0f + expf(-sy));
                    sz = sz / (1.0f + expf(-sz));
                    sw = sw / (1.0f + expf(-sw));
                    if (bi != cur) {
                        if (cur >= 0) {
                            atomicAdd(&pooled[cur * 64 + c0 + 0], rx);
                            atomicAdd(&pooled[cur * 64 + c0 + 1], ry);
                            atomicAdd(&pooled[cur * 64 + c0 + 2], rz);
                            atomicAdd(&pooled[cur * 64 + c0 + 3], rw);
                        }
                        cur = bi; rx = sx; ry = sy; rz = sz; rw = sw;
                    } else {
                        rx += sx; ry += sy; rz += sz; rw += sw;
                    }
                }
            }
            if (cur >= 0) {
                atomicAdd(&pooled[cur * 64 + c0 + 0], rx);
                atomicAdd(&pooled[cur * 64 + c0 + 1], ry);
                atomicAdd(&pooled[cur * 64 + c0 + 2], rz);
                atomicAdd(&pooled[cur * 64 + c0 + 3], rw);
            }
        }
    }
}

// ---------------- gather: agg[d] = dis[d] * (g[d] + sum_{s in N(d)} g[s]) ----------------
__global__ __launch_bounds__(256) void k_gather(const int* __restrict__ csr_src,
                                                const int* __restrict__ rowptr,
                                                const float* __restrict__ dis,
                                                const float* __restrict__ g,
                                                float* __restrict__ agg, int N) {
    int node = blockIdx.x * 4 + (threadIdx.x >> 6);
    if (node >= N) return;
    int lane = threadIdx.x & 63;
    int grp  = lane >> 4;      // 0..3 edge groups
    int f4   = lane & 15;      // feature quad
    int beg  = rowptr[node];
    int end  = rowptr[node + 1];

    float ax = 0.f, ay = 0.f, az = 0.f, aw = 0.f;
    for (int i = beg + grp; i < end; i += 4) {
        int s = csr_src[i];
        float4 v = ((const float4*)(g + (size_t)s * 64))[f4];
        ax += v.x; ay += v.y; az += v.z; aw += v.w;
    }
    ax += __shfl_xor(ax, 16); ay += __shfl_xor(ay, 16);
    az += __shfl_xor(az, 16); aw += __shfl_xor(aw, 16);
    ax += __shfl_xor(ax, 32); ay += __shfl_xor(ay, 32);
    az += __shfl_xor(az, 32); aw += __shfl_xor(aw, 32);

    if (grp == 0) {
        float dd = dis[node];
        float4 s4 = ((const float4*)(g + (size_t)node * 64))[f4];   // self term
        float4 o = make_float4(dd * (ax + s4.x), dd * (ay + s4.y),
                               dd * (az + s4.z), dd * (aw + s4.w));
        ((float4*)(agg + (size_t)node * 64))[f4] = o;
    }
}

// ---------------- readout ----------------
__global__ __launch_bounds__(256) void k_readout(const float* __restrict__ pooled,
                                                 const float* __restrict__ Wout,
                                                 const float* __restrict__ bout,
                                                 float* __restrict__ out) {
    int idx = blockIdx.x * 256 + threadIdx.x;
    if (idx >= N_GRAPHS * N_CLASSES) return;
    int g = idx / N_CLASSES, c = idx % N_CLASSES;
    float s = bout[c];
    #pragma unroll
    for (int j = 0; j < 64; ++j) s += pooled[g * 64 + j] * Wout[j * N_CLASSES + c];
    out[idx] = fmaxf(s, 0.0f);
}

extern "C" void kernel_launch(void* const* d_in, const int* in_sizes, int n_in,
                              void* d_out, int out_size, void* d_ws, size_t ws_size,
                              hipStream_t stream) {
    const float* x      = (const float*)d_in[0];
    const int*   ei     = (const int*)d_in[1];
    const int*   batch  = (const int*)d_in[2];
    const float* W_enc  = (const float*)d_in[3];
    const float* b_enc  = (const float*)d_in[4];
    const float* W_conv = (const float*)d_in[5];
    const float* b_conv = (const float*)d_in[6];
    const float* W_out  = (const float*)d_in[7];
    const float* b_out  = (const float*)d_in[8];
    float* out = (float*)d_out;

    const int N = in_sizes[2];
    const int E = in_sizes[1] / 2;
    const int* src = ei;
    const int* dst = ei + E;
    const int nbuckets = (N + BNODES - 1) >> BSH;

    char* ws = (char*)d_ws;
    size_t off = 0;
    auto alloc = [&](size_t bytes) -> char* {
        char* p = ws + off;
        off += (bytes + 255) & ~(size_t)255;
        return p;
    };
    int*   cnt     = (int*)alloc((size_t)N * sizeof(int));
    int*   rowptr  = (int*)alloc((size_t)(N + 1) * sizeof(int));
    int*   partial = (int*)alloc(1024 * sizeof(int));
    int*   bcur    = (int*)alloc((size_t)(nbuckets + 1) * sizeof(int));
    int*   packed  = (int*)alloc((size_t)E * sizeof(int));
    int*   csr_src = (int*)alloc((size_t)E * sizeof(int));
    float* dis     = (float*)alloc((size_t)N * sizeof(float));
    float* G       = (float*)alloc((size_t)N * HIDDEN * sizeof(float));
    float* AGG     = (float*)alloc((size_t)N * HIDDEN * sizeof(float));
    float* pooled  = (float*)alloc((size_t)N_GRAPHS * HIDDEN * sizeof(float));
    (void)ws_size;

    int nb_e = (E + 255) / 256;
    int nb_s = (N + 1023) / 1024;   // 98 <= 256

    hipMemsetAsync(cnt, 0, (size_t)N * sizeof(int), stream);
    hipMemsetAsync(pooled, 0, (size_t)N_GRAPHS * HIDDEN * sizeof(float), stream);

    k_count<<<nb_e, 256, 0, stream>>>(dst, cnt, E);
    k_scan1<<<nb_s, 256, 0, stream>>>(cnt, partial, N);
    k_scan2<<<1,    256, 0, stream>>>(partial, nb_s);
    k_scan3<<<nb_s, 256, 0, stream>>>(cnt, partial, rowptr, dis, bcur, N, E);
    k_bin  <<<nb_e, 256, 0, stream>>>(src, dst, bcur, packed, E);
    k_fill2<<<nbuckets, 256, 0, stream>>>(packed, rowptr, csr_src, N, nbuckets);

    int nchunks = (N + 63) / 64;
    int ggrid = 1024;
    // encoder: G = dis * (x @ W_enc + b_enc)
    k_gemm<<<ggrid, 256, 0, stream>>>(x, W_enc, b_enc, dis, batch, G, pooled, N, nchunks, 0);

    for (int l = 0; l < N_LAYERS; ++l) {
        // AGG = dis * (G + neighbor_sum(G))
        k_gather<<<(N + 3) / 4, 256, 0, stream>>>(csr_src, rowptr, dis, G, AGG, N);
        int mode = (l == N_LAYERS - 1) ? 2 : 1;
        // mid: G = dis * silu(AGG @ Wl + bl);  last: pooled += silu(AGG @ Wl + bl)
        k_gemm<<<ggrid, 256, 0, stream>>>(AGG, W_conv + (size_t)l * HIDDEN * HIDDEN,
                                          b_conv + (size_t)l * HIDDEN, dis, batch,
                                          G, pooled, N, nchunks, mode);
    }

    k_readout<<<(N_GRAPHS * N_CLASSES + 255) / 256, 256, 0, stream>>>(pooled, W_out, b_out, out);
}

// Round 6
// 571.106 us; speedup vs baseline: 1.2651x; 1.2651x over previous
//
#include <hip/hip_runtime.h>
#include <math.h>

#define HIDDEN 64
#define N_LAYERS 4
#define N_CLASSES 10
#define N_GRAPHS 512
#define BSH 8                        // coarse bucket: 256 nodes
#define NPB 256                      // nodes per bucket
#define PART_K 8192                  // edges per partition block
// NB = ceil(N/256) must be <= 511 (N <= ~130k). N=100000 -> NB=391.

// ---------------- pass 1: global bucket histogram ----------------
__global__ __launch_bounds__(256) void k_histA(const int* __restrict__ dst,
                                               int* __restrict__ ghist, int E, int NB) {
    __shared__ int hist[512];
    int t = threadIdx.x;
    hist[t] = 0; hist[t + 256] = 0;
    __syncthreads();
    int base = blockIdx.x * PART_K;
    int kend = min(PART_K, E - base);
    for (int k = t; k < kend; k += 256) atomicAdd(&hist[dst[base + k] >> BSH], 1);
    __syncthreads();
    for (int j = t; j < NB; j += 256) {
        int h = hist[j];
        if (h) atomicAdd(&ghist[j], h);
    }
}

// ---------------- pass 2: scan bucket sizes -> bases, init cursors ----------------
__global__ __launch_bounds__(256) void k_bucketscan(const int* __restrict__ ghist,
                                                    int* __restrict__ bucketbase,
                                                    int* __restrict__ gcur, int NB) {
    __shared__ int s[256];
    int t = threadIdx.x;
    int j0 = 2 * t, j1 = 2 * t + 1;
    int h0 = (j0 < NB) ? ghist[j0] : 0;
    int h1 = (j1 < NB) ? ghist[j1] : 0;
    s[t] = h0 + h1; __syncthreads();
    for (int o = 1; o < 256; o <<= 1) {
        int x = (t >= o) ? s[t - o] : 0;
        __syncthreads();
        s[t] += x;
        __syncthreads();
    }
    int base = (t == 0) ? 0 : s[t - 1];
    if (j0 <= NB) { bucketbase[j0] = base;      gcur[j0] = base; }
    if (j1 <= NB) { bucketbase[j1] = base + h0; gcur[j1] = base + h0; }
}

// ---------------- pass 3: partition edges into bucket segments (LDS reorder) ----------------
__global__ __launch_bounds__(256) void k_partition(const int* __restrict__ src,
                                                   const int* __restrict__ dst,
                                                   int* __restrict__ gcur,
                                                   int* __restrict__ packed,
                                                   int E, int NB) {
    __shared__ int hist[512];
    __shared__ int scanE[512];
    __shared__ int cur[512];
    __shared__ int delta[512];
    __shared__ int ps[256];
    __shared__ int stage[PART_K];
    int t = threadIdx.x;
    int base = blockIdx.x * PART_K;
    int kend = min(PART_K, E - base);

    hist[t] = 0; hist[t + 256] = 0;
    __syncthreads();
    for (int k = t; k < kend; k += 256) atomicAdd(&hist[dst[base + k] >> BSH], 1);
    __syncthreads();

    // exclusive scan of hist[0..511] (pairs per thread)
    int j0 = 2 * t, j1 = j0 + 1;
    int h0 = hist[j0], h1 = hist[j1];
    ps[t] = h0 + h1; __syncthreads();
    for (int o = 1; o < 256; o <<= 1) {
        int x = (t >= o) ? ps[t - o] : 0;
        __syncthreads();
        ps[t] += x;
        __syncthreads();
    }
    int bexc = (t == 0) ? 0 : ps[t - 1];
    scanE[j0] = bexc;
    scanE[j1] = bexc + h0;
    __syncthreads();

    // reserve global ranges, one atomic per non-empty bucket
    for (int j = t; j < NB; j += 256) {
        int h = hist[j];
        int g = h ? atomicAdd(&gcur[j], h) : 0;
        delta[j] = g - scanE[j];
        cur[j]   = scanE[j];
    }
    __syncthreads();

    // scatter into LDS stage, grouped by bucket
    for (int k = t; k < kend; k += 256) {
        int d = dst[base + k], s = src[base + k];
        int j = d >> BSH;
        int pos = atomicAdd(&cur[j], 1);
        stage[pos] = (s << BSH) | (d & (NPB - 1));
    }
    __syncthreads();

    // linear write-out: consecutive i -> consecutive global within each run
    for (int i = t; i < kend; i += 256) {
        int lo = 0, hi = NB;
        while (hi - lo > 1) {
            int mid = (lo + hi) >> 1;
            if (scanE[mid] <= i) lo = mid; else hi = mid;
        }
        packed[i + delta[lo]] = stage[i];
    }
}

// ---------------- pass 4: per-bucket CSR fill; emits rowptr + dis too ----------------
__global__ __launch_bounds__(256) void k_fill3(const int* __restrict__ packed,
                                               const int* __restrict__ bucketbase,
                                               int* __restrict__ rowptr,
                                               float* __restrict__ dis,
                                               int* __restrict__ csr_src,
                                               int N, int E) {
    __shared__ int cnt[256];
    __shared__ int rp[256];
    int j = blockIdx.x;
    int t = threadIdx.x;
    int node0 = j << BSH;
    int segb = bucketbase[j];
    int sege = bucketbase[j + 1];

    cnt[t] = 0; __syncthreads();
    for (int i = segb + t; i < sege; i += 256) atomicAdd(&cnt[packed[i] & (NPB - 1)], 1);
    __syncthreads();

    int c = cnt[t];
    rp[t] = c; __syncthreads();
    for (int o = 1; o < 256; o <<= 1) {
        int x = (t >= o) ? rp[t - o] : 0;
        __syncthreads();
        rp[t] += x;
        __syncthreads();
    }
    int start = segb + rp[t] - c;   // exclusive
    int node = node0 + t;
    if (node < N) {
        rowptr[node] = start;
        dis[node] = rsqrtf((float)c + 1.0f);   // + self-loop
        if (node == N - 1) rowptr[N] = E;
    }
    __syncthreads();
    cnt[t] = start;                 // reuse as cursor
    __syncthreads();
    for (int i = segb + t; i < sege; i += 256) {
        int v = packed[i];
        int slot = atomicAdd(&cnt[v & (NPB - 1)], 1);
        csr_src[slot] = v >> BSH;
    }
}

// ---------------- GEMM: [N,64] @ [64,64], grid-stride 64-row chunks ----------------
// mode 0 (encoder):  outg[r] = dis[r] * (v + b)
// mode 1 (mid layer):outg[r] = dis[r] * silu(v + b)
// mode 2 (last):     pooled[batch[r]] += silu(v + b)   (atomic, batch-run combined)
__global__ __launch_bounds__(256, 4) void k_gemm(const float* __restrict__ in,
                                                 const float* __restrict__ W,
                                                 const float* __restrict__ bias,
                                                 const float* __restrict__ dis,
                                                 const int* __restrict__ batch,
                                                 float* __restrict__ outg,
                                                 float* __restrict__ pooled,
                                                 int N, int nchunks, int mode) {
    __shared__ float Ws[64 * 64];
    int tid = threadIdx.x;
    #pragma unroll
    for (int i = 0; i < 4; ++i)
        ((float4*)Ws)[tid + i * 256] = ((const float4*)W)[tid + i * 256];
    __syncthreads();

    int cq = tid & 15;
    int rg = tid >> 4;
    int c0 = cq * 4;
    float4 b4 = *(const float4*)(bias + c0);

    for (int chunk = blockIdx.x; chunk < nchunks; chunk += gridDim.x) {
        int row0 = chunk * 64 + rg * 4;
        const float4* xr0 = (const float4*)(in + (size_t)((row0 + 0 < N) ? row0 + 0 : 0) * 64);
        const float4* xr1 = (const float4*)(in + (size_t)((row0 + 1 < N) ? row0 + 1 : 0) * 64);
        const float4* xr2 = (const float4*)(in + (size_t)((row0 + 2 < N) ? row0 + 2 : 0) * 64);
        const float4* xr3 = (const float4*)(in + (size_t)((row0 + 3 < N) ? row0 + 3 : 0) * 64);

        float4 a0 = make_float4(0.f, 0.f, 0.f, 0.f);
        float4 a1 = a0, a2 = a0, a3 = a0;

        #pragma unroll 4
        for (int kc = 0; kc < 16; ++kc) {
            float4 x0 = xr0[kc];
            float4 x1 = xr1[kc];
            float4 x2 = xr2[kc];
            float4 x3 = xr3[kc];
            float4 w0 = *(const float4*)(Ws + (kc * 4 + 0) * 64 + c0);
            float4 w1 = *(const float4*)(Ws + (kc * 4 + 1) * 64 + c0);
            float4 w2 = *(const float4*)(Ws + (kc * 4 + 2) * 64 + c0);
            float4 w3 = *(const float4*)(Ws + (kc * 4 + 3) * 64 + c0);
            #define ROWFMA(ACC, XV)                                             \
                ACC.x += XV.x * w0.x + XV.y * w1.x + XV.z * w2.x + XV.w * w3.x; \
                ACC.y += XV.x * w0.y + XV.y * w1.y + XV.z * w2.y + XV.w * w3.y; \
                ACC.z += XV.x * w0.z + XV.y * w1.z + XV.z * w2.z + XV.w * w3.z; \
                ACC.w += XV.x * w0.w + XV.y * w1.w + XV.z * w2.w + XV.w * w3.w;
            ROWFMA(a0, x0)
            ROWFMA(a1, x1)
            ROWFMA(a2, x2)
            ROWFMA(a3, x3)
            #undef ROWFMA
        }

        float4 acc[4] = {a0, a1, a2, a3};
        if (mode == 0) {
            #pragma unroll
            for (int i = 0; i < 4; ++i) {
                int r = row0 + i;
                if (r < N) {
                    float ds = dis[r];
                    float4 v = acc[i];
                    float4 o = make_float4(ds * (v.x + b4.x), ds * (v.y + b4.y),
                                           ds * (v.z + b4.z), ds * (v.w + b4.w));
                    *(float4*)(outg + (size_t)r * 64 + c0) = o;
                }
            }
        } else if (mode == 1) {
            #pragma unroll
            for (int i = 0; i < 4; ++i) {
                int r = row0 + i;
                if (r < N) {
                    float ds = dis[r];
                    float4 v = acc[i];
                    float sx = v.x + b4.x, sy = v.y + b4.y, sz = v.z + b4.z, sw = v.w + b4.w;
                    float4 o;
                    o.x = ds * (sx / (1.0f + expf(-sx)));
                    o.y = ds * (sy / (1.0f + expf(-sy)));
                    o.z = ds * (sz / (1.0f + expf(-sz)));
                    o.w = ds * (sw / (1.0f + expf(-sw)));
                    *(float4*)(outg + (size_t)r * 64 + c0) = o;
                }
            }
        } else {
            float rx = 0.f, ry = 0.f, rz = 0.f, rw = 0.f;
            int cur = -1;
            #pragma unroll
            for (int i = 0; i < 4; ++i) {
                int r = row0 + i;
                if (r < N) {
                    int bi = batch[r];
                    float4 v = acc[i];
                    float sx = v.x + b4.x, sy = v.y + b4.y, sz = v.z + b4.z, sw = v.w + b4.w;
                    sx = sx / (1.0f + expf(-sx));
                    sy = sy / (1.0f + expf(-sy));
                    sz = sz / (1.0f + expf(-sz));
                    sw = sw / (1.0f + expf(-sw));
                    if (bi != cur) {
                        if (cur >= 0) {
                            atomicAdd(&pooled[cur * 64 + c0 + 0], rx);
                            atomicAdd(&pooled[cur * 64 + c0 + 1], ry);
                            atomicAdd(&pooled[cur * 64 + c0 + 2], rz);
                            atomicAdd(&pooled[cur * 64 + c0 + 3], rw);
                        }
                        cur = bi; rx = sx; ry = sy; rz = sz; rw = sw;
                    } else {
                        rx += sx; ry += sy; rz += sz; rw += sw;
                    }
                }
            }
            if (cur >= 0) {
                atomicAdd(&pooled[cur * 64 + c0 + 0], rx);
                atomicAdd(&pooled[cur * 64 + c0 + 1], ry);
                atomicAdd(&pooled[cur * 64 + c0 + 2], rz);
                atomicAdd(&pooled[cur * 64 + c0 + 3], rw);
            }
        }
    }
}

// ---------------- gather: agg[d] = dis[d] * (g[d] + sum_{s in N(d)} g[s]) ----------------
__global__ __launch_bounds__(256) void k_gather(const int* __restrict__ csr_src,
                                                const int* __restrict__ rowptr,
                                                const float* __restrict__ dis,
                                                const float* __restrict__ g,
                                                float* __restrict__ agg, int N) {
    int node = blockIdx.x * 4 + (threadIdx.x >> 6);
    if (node >= N) return;
    int lane = threadIdx.x & 63;
    int grp  = lane >> 4;
    int f4   = lane & 15;
    int beg  = rowptr[node];
    int end  = rowptr[node + 1];

    float ax = 0.f, ay = 0.f, az = 0.f, aw = 0.f;
    for (int i = beg + grp; i < end; i += 4) {
        int s = csr_src[i];
        float4 v = ((const float4*)(g + (size_t)s * 64))[f4];
        ax += v.x; ay += v.y; az += v.z; aw += v.w;
    }
    ax += __shfl_xor(ax, 16); ay += __shfl_xor(ay, 16);
    az += __shfl_xor(az, 16); aw += __shfl_xor(aw, 16);
    ax += __shfl_xor(ax, 32); ay += __shfl_xor(ay, 32);
    az += __shfl_xor(az, 32); aw += __shfl_xor(aw, 32);

    if (grp == 0) {
        float dd = dis[node];
        float4 s4 = ((const float4*)(g + (size_t)node * 64))[f4];
        float4 o = make_float4(dd * (ax + s4.x), dd * (ay + s4.y),
                               dd * (az + s4.z), dd * (aw + s4.w));
        ((float4*)(agg + (size_t)node * 64))[f4] = o;
    }
}

// ---------------- readout ----------------
__global__ __launch_bounds__(256) void k_readout(const float* __restrict__ pooled,
                                                 const float* __restrict__ Wout,
                                                 const float* __restrict__ bout,
                                                 float* __restrict__ out) {
    int idx = blockIdx.x * 256 + threadIdx.x;
    if (idx >= N_GRAPHS * N_CLASSES) return;
    int g = idx / N_CLASSES, c = idx % N_CLASSES;
    float s = bout[c];
    #pragma unroll
    for (int j = 0; j < 64; ++j) s += pooled[g * 64 + j] * Wout[j * N_CLASSES + c];
    out[idx] = fmaxf(s, 0.0f);
}

extern "C" void kernel_launch(void* const* d_in, const int* in_sizes, int n_in,
                              void* d_out, int out_size, void* d_ws, size_t ws_size,
                              hipStream_t stream) {
    const float* x      = (const float*)d_in[0];
    const int*   ei     = (const int*)d_in[1];
    const int*   batch  = (const int*)d_in[2];
    const float* W_enc  = (const float*)d_in[3];
    const float* b_enc  = (const float*)d_in[4];
    const float* W_conv = (const float*)d_in[5];
    const float* b_conv = (const float*)d_in[6];
    const float* W_out  = (const float*)d_in[7];
    const float* b_out  = (const float*)d_in[8];
    float* out = (float*)d_out;

    const int N = in_sizes[2];
    const int E = in_sizes[1] / 2;
    const int* src = ei;
    const int* dst = ei + E;
    const int NB   = (N + NPB - 1) >> BSH;    // 391 coarse buckets
    const int NBLK = (E + PART_K - 1) / PART_K;

    char* ws = (char*)d_ws;
    size_t off = 0;
    auto alloc = [&](size_t bytes) -> char* {
        char* p = ws + off;
        off += (bytes + 255) & ~(size_t)255;
        return p;
    };
    int*   ghist      = (int*)alloc((size_t)(NB + 1) * sizeof(int));
    int*   bucketbase = (int*)alloc((size_t)(NB + 1) * sizeof(int));
    int*   gcur       = (int*)alloc((size_t)(NB + 1) * sizeof(int));
    int*   packed     = (int*)alloc((size_t)E * sizeof(int));
    int*   csr_src    = (int*)alloc((size_t)E * sizeof(int));
    int*   rowptr     = (int*)alloc((size_t)(N + 1) * sizeof(int));
    float* dis        = (float*)alloc((size_t)N * sizeof(float));
    float* G          = (float*)alloc((size_t)N * HIDDEN * sizeof(float));
    float* AGG        = (float*)alloc((size_t)N * HIDDEN * sizeof(float));
    float* pooled     = (float*)alloc((size_t)N_GRAPHS * HIDDEN * sizeof(float));
    (void)ws_size;

    hipMemsetAsync(ghist, 0, (size_t)(NB + 1) * sizeof(int), stream);
    hipMemsetAsync(pooled, 0, (size_t)N_GRAPHS * HIDDEN * sizeof(float), stream);

    k_histA     <<<NBLK, 256, 0, stream>>>(dst, ghist, E, NB);
    k_bucketscan<<<1,    256, 0, stream>>>(ghist, bucketbase, gcur, NB);
    k_partition <<<NBLK, 256, 0, stream>>>(src, dst, gcur, packed, E, NB);
    k_fill3     <<<NB,   256, 0, stream>>>(packed, bucketbase, rowptr, dis, csr_src, N, E);

    int nchunks = (N + 63) / 64;
    int ggrid = 1024;
    // encoder: G = dis * (x @ W_enc + b_enc)
    k_gemm<<<ggrid, 256, 0, stream>>>(x, W_enc, b_enc, dis, batch, G, pooled, N, nchunks, 0);

    for (int l = 0; l < N_LAYERS; ++l) {
        // AGG = dis * (G + neighbor_sum(G))
        k_gather<<<(N + 3) / 4, 256, 0, stream>>>(csr_src, rowptr, dis, G, AGG, N);
        int mode = (l == N_LAYERS - 1) ? 2 : 1;
        // mid: G = dis * silu(AGG @ Wl + bl);  last: pooled += silu(AGG @ Wl + bl)
        k_gemm<<<ggrid, 256, 0, stream>>>(AGG, W_conv + (size_t)l * HIDDEN * HIDDEN,
                                          b_conv + (size_t)l * HIDDEN, dis, batch,
                                          G, pooled, N, nchunks, mode);
    }

    k_readout<<<(N_GRAPHS * N_CLASSES + 255) / 256, 256, 0, stream>>>(pooled, W_out, b_out, out);
}